// Round 1
// baseline (265.833 us; speedup 1.0000x reference)
//
#include <hip/hip_runtime.h>
#include <stdint.h>

#define DIM 768
#define HEADS 12
#define SEQ 196
#define BATCH 64
#define NTOK (BATCH*SEQ)   // 12544
#define SCALE 0.125f       // 64^-0.5

using short8  = __attribute__((ext_vector_type(8))) short;
using float4v = __attribute__((ext_vector_type(4))) float;
using ushort4v = __attribute__((ext_vector_type(4))) unsigned short;

static __device__ __forceinline__ unsigned short f2bf(float f) {
  union { float f; unsigned u; } v; v.f = f;
  unsigned u = v.u;
  u += 0x7fffu + ((u >> 16) & 1u);   // RNE
  return (unsigned short)(u >> 16);
}

#if defined(__has_builtin)
#if __has_builtin(__builtin_amdgcn_global_load_lds)
#define HAS_GLL 1
#endif
#endif

// Stage 16B/lane: global (per-lane ptr g) -> LDS (wave-uniform base l, lane*16B apart)
static __device__ __forceinline__ void gll16(const unsigned short* g, unsigned short* l) {
#ifdef HAS_GLL
  __builtin_amdgcn_global_load_lds(
      (const __attribute__((address_space(1))) void*)g,
      (__attribute__((address_space(3))) void*)l, 16, 0, 0);
#else
  const int lane = threadIdx.x & 63;
  *(short8*)(l + lane * 8) = *(const short8*)g;
#endif
}

// ---------------- pre-pass: cast x fp32 -> bf16 ----------------
__global__ __launch_bounds__(256) void cast_x_kernel(const float* __restrict__ in,
                                                     unsigned short* __restrict__ out) {
  int i = blockIdx.x * 256 + threadIdx.x;      // exactly NTOK*DIM/4 threads
  float4 v = ((const float4*)in)[i];
  ushort4v o;
  o.x = f2bf(v.x); o.y = f2bf(v.y); o.z = f2bf(v.z); o.w = f2bf(v.w);
  ((ushort4v*)out)[i] = o;
}

// ---------------- pre-pass: transpose + cast W [R][C] fp32 -> Wt [C][R] bf16 ----------------
__global__ __launch_bounds__(256) void transpose_cast_kernel(const float* __restrict__ in,
                                                             unsigned short* __restrict__ out,
                                                             int R, int C) {
  __shared__ float tile[32][33];
  int c0 = blockIdx.x * 32, r0 = blockIdx.y * 32;
  int tx = threadIdx.x, ty = threadIdx.y;      // (32,8)
  for (int i = 0; i < 32; i += 8)
    tile[ty + i][tx] = in[(size_t)(r0 + ty + i) * C + c0 + tx];
  __syncthreads();
  for (int i = 0; i < 32; i += 8)
    out[(size_t)(c0 + ty + i) * R + r0 + tx] = f2bf(tile[tx][ty + i]);
}

// ---------------- GEMM: C[M][N] = A[M][768] * Bt[N][768]^T, 128x128 tile ----------------
// MODE 0: write bf16 QKV scattered into [3][B][H][S][64]
// MODE 1: write fp32 out[m][n] + bias[n]
template <int MODE>
__global__ __launch_bounds__(256) void gemm_kernel(const unsigned short* __restrict__ A,
                                                   const unsigned short* __restrict__ Bt,
                                                   const float* __restrict__ bias,
                                                   unsigned short* __restrict__ outQKV,
                                                   float* __restrict__ outF) {
  constexpr int K = 768;
  __shared__ __align__(16) unsigned short Als[128 * 32];
  __shared__ __align__(16) unsigned short Bls[128 * 32];
  const int tid = threadIdx.x;
  const int wid = tid >> 6, lane = tid & 63;
  const int s = lane & 15, q = lane >> 4;
  const int wr = wid >> 1, wc = wid & 1;           // 2x2 wave grid, 64x64 per wave
  const int m0 = blockIdx.y * 128;
  const int n0 = blockIdx.x * 128;

  float4v acc[4][4];
  for (int i = 0; i < 4; i++)
    for (int j = 0; j < 4; j++) acc[i][j] = (float4v){0.f, 0.f, 0.f, 0.f};

  const int srow = lane >> 2;           // 0..15
  const int scol = (lane & 3) * 8;      // elements (16B)

  for (int kt = 0; kt < K; kt += 32) {
    const unsigned short* ga = A  + (size_t)(m0 + wid * 32 + srow) * K + kt + scol;
    const unsigned short* gb = Bt + (size_t)(n0 + wid * 32 + srow) * K + kt + scol;
    unsigned short* la = &Als[wid * 32 * 32];
    unsigned short* lb = &Bls[wid * 32 * 32];
    gll16(ga,           la);
    gll16(ga + 16 * K,  la + 16 * 32);
    gll16(gb,           lb);
    gll16(gb + 16 * K,  lb + 16 * 32);
    __syncthreads();   // drains vmcnt -> staged data visible

    short8 af[4], bf[4];
    for (int i = 0; i < 4; i++)
      af[i] = *(const short8*)&Als[(wr * 64 + i * 16 + s) * 32 + q * 8];
    for (int j = 0; j < 4; j++)
      bf[j] = *(const short8*)&Bls[(wc * 64 + j * 16 + s) * 32 + q * 8];
    for (int i = 0; i < 4; i++)
      for (int j = 0; j < 4; j++)
        acc[i][j] = __builtin_amdgcn_mfma_f32_16x16x32_bf16(af[i], bf[j], acc[i][j], 0, 0, 0);
    __syncthreads();   // before next overwrite
  }

  // epilogue: C/D layout col = lane&15, row = q*4 + reg
  for (int i = 0; i < 4; i++) {
    int mbase = m0 + wr * 64 + i * 16 + q * 4;
    for (int j = 0; j < 4; j++) {
      int ng = n0 + wc * 64 + j * 16 + s;
      if (MODE == 0) {
        int t = ng / 768, rem = ng % 768;
        int h = rem >> 6, d = rem & 63;
        for (int r = 0; r < 4; r++) {
          int mg = mbase + r;
          int b = mg / 196, ns = mg - b * 196;
          size_t off = ((size_t)((t * BATCH + b) * HEADS + h) * SEQ + ns) * 64 + d;
          outQKV[off] = f2bf(acc[i][j][r]);
        }
      } else {
        float bv = bias[ng];
        for (int r = 0; r < 4; r++)
          outF[(size_t)(mbase + r) * 768 + ng] = acc[i][j][r] + bv;
      }
    }
  }
}

// ---------------- attention: one block per (b,h) ----------------
__global__ __launch_bounds__(256) void attn_kernel(const unsigned short* __restrict__ qkv,
                                                   const float* __restrict__ static_a,
                                                   unsigned short* __restrict__ outA) {
  constexpr int WV = 232;                 // padded width (bank-balanced, 16B-aligned rows)
  __shared__ __align__(16) unsigned short Vt[64 * WV];        // V^T: [d][m]
  __shared__ __align__(16) unsigned short Aw[4 * 16 * WV];    // per-wave P slab [16][WV]
  const int tid = threadIdx.x, wid = tid >> 6, lane = tid & 63;
  const int s = lane & 15, q = lane >> 4;
  const int bh = blockIdx.x;
  const int b = bh / 12, h = bh % 12;
  const size_t slab = (size_t)SEQ * 64;
  const unsigned short* Qb = qkv + (size_t)(0 * BATCH * HEADS + bh) * slab;
  const unsigned short* Kb = qkv + (size_t)(1 * BATCH * HEADS + bh) * slab;
  const unsigned short* Vb = qkv + (size_t)(2 * BATCH * HEADS + bh) * slab;

  // stage V^T
  for (int idx = tid; idx < SEQ * 16; idx += 256) {
    int m = idx >> 4;
    int d4 = (idx & 15) * 4;
    ushort4v v = *(const ushort4v*)&Vb[m * 64 + d4];
    Vt[(d4 + 0) * WV + m] = v.x; Vt[(d4 + 1) * WV + m] = v.y;
    Vt[(d4 + 2) * WV + m] = v.z; Vt[(d4 + 3) * WV + m] = v.w;
  }
  for (int idx = tid; idx < 64 * 28; idx += 256) {   // zero pad m in [196,224)
    int d = idx / 28, m = 196 + idx % 28;
    Vt[d * WV + m] = 0;
  }
  __syncthreads();

  for (int qt = wid; qt < 13; qt += 4) {
    int n0 = qt * 16;
    int qrow = n0 + s; if (qrow > 195) qrow = 195;
    short8 qf0 = *(const short8*)&Qb[qrow * 64 + q * 8];
    short8 qf1 = *(const short8*)&Qb[qrow * 64 + 32 + q * 8];

    // S = Q K^T: A-frag = Q rows, B-frag = K rows (both 16B contiguous in global)
    float4v sacc[13];
    for (int mt = 0; mt < 13; mt++) {
      int mrow = mt * 16 + s; if (mrow > 195) mrow = 195;
      short8 kf0 = *(const short8*)&Kb[mrow * 64 + q * 8];
      short8 kf1 = *(const short8*)&Kb[mrow * 64 + 32 + q * 8];
      float4v z = (float4v){0.f, 0.f, 0.f, 0.f};
      z = __builtin_amdgcn_mfma_f32_16x16x32_bf16(qf0, kf0, z, 0, 0, 0);
      z = __builtin_amdgcn_mfma_f32_16x16x32_bf16(qf1, kf1, z, 0, 0, 0);
      sacc[mt] = z;
    }

    // row softmax over 196 cols (C-layout: this lane holds col s of each tile, rows q*4+i)
    bool lastvalid = (s < 4);
    float mx[4], sm[4];
    for (int i = 0; i < 4; i++) mx[i] = -3.0e38f;
    for (int mt = 0; mt < 13; mt++) {
      bool v = (mt < 12) || lastvalid;
      if (v)
        for (int i = 0; i < 4; i++) mx[i] = fmaxf(mx[i], sacc[mt][i] * SCALE);
    }
    for (int off = 1; off < 16; off <<= 1)
      for (int i = 0; i < 4; i++) mx[i] = fmaxf(mx[i], __shfl_xor(mx[i], off, 16));
    for (int i = 0; i < 4; i++) sm[i] = 0.f;
    for (int mt = 0; mt < 13; mt++) {
      bool v = (mt < 12) || lastvalid;
      for (int i = 0; i < 4; i++) {
        float e = v ? __expf(sacc[mt][i] * SCALE - mx[i]) : 0.f;
        sacc[mt][i] = e;
        sm[i] += e;
      }
    }
    for (int off = 1; off < 16; off <<= 1)
      for (int i = 0; i < 4; i++) sm[i] += __shfl_xor(sm[i], off, 16);
    float inv[4];
    for (int i = 0; i < 4; i++) inv[i] = 1.0f / sm[i];

    // P = softmax + static_a -> per-wave LDS slab (C-layout -> A-layout round trip)
    unsigned short* Arow = &Aw[wid * 16 * WV];
    for (int mt = 0; mt < 13; mt++) {
      bool v = (mt < 12) || lastvalid;
      int m = mt * 16 + s;
      for (int i = 0; i < 4; i++) {
        int n = n0 + q * 4 + i; int ncl = n > 195 ? 195 : n;
        float a = 0.f;
        if (v) a = sacc[mt][i] * inv[i] + static_a[(h * SEQ + ncl) * SEQ + m];
        Arow[(q * 4 + i) * WV + m] = f2bf(a);
      }
    }
    { // zero pad cols [208,224)
      int m = 208 + s;
      for (int i = 0; i < 4; i++) Arow[(q * 4 + i) * WV + m] = 0;
    }
    asm volatile("s_waitcnt lgkmcnt(0)" ::: "memory");  // wave-local LDS visibility

    // O = P V : A-frag rows = lane&15 from Arow, B-frag = Vt rows
    short8 af[7];
    for (int ks = 0; ks < 7; ks++)
      af[ks] = *(const short8*)&Arow[s * WV + ks * 32 + q * 8];
    for (int dt = 0; dt < 4; dt++) {
      float4v o = (float4v){0.f, 0.f, 0.f, 0.f};
      for (int ks = 0; ks < 7; ks++) {
        short8 vf = *(const short8*)&Vt[(dt * 16 + s) * WV + ks * 32 + q * 8];
        o = __builtin_amdgcn_mfma_f32_16x16x32_bf16(af[ks], vf, o, 0, 0, 0);
      }
      for (int i = 0; i < 4; i++) {
        int ng = n0 + q * 4 + i;
        if (ng < 196) {
          size_t off = ((size_t)(b * SEQ + ng) * DIM) + h * 64 + dt * 16 + s;
          outA[off] = f2bf(o[i]);
        }
      }
    }
  }
}

extern "C" void kernel_launch(void* const* d_in, const int* in_sizes, int n_in,
                              void* d_out, int out_size, void* d_ws, size_t ws_size,
                              hipStream_t stream) {
  const float* x        = (const float*)d_in[0];
  const float* Wqkv     = (const float*)d_in[1];
  const float* static_a = (const float*)d_in[2];
  const float* Wproj    = (const float*)d_in[3];
  const float* bproj    = (const float*)d_in[4];
  float* out = (float*)d_out;

  unsigned char* ws = (unsigned char*)d_ws;
  size_t off = 0;
  unsigned short* qkv_ws = (unsigned short*)(ws + off); off += (size_t)3 * NTOK * DIM * 2; // 57.8 MB
  unsigned short* xa_ws  = (unsigned short*)(ws + off); off += (size_t)NTOK * DIM * 2;     // x_bf16, reused as attn-out
  unsigned short* wqkvt  = (unsigned short*)(ws + off); off += (size_t)3 * DIM * DIM * 2;  // W_qkv^T bf16
  unsigned short* wprojt = (unsigned short*)(ws + off); off += (size_t)DIM * DIM * 2;      // W_proj^T bf16

  cast_x_kernel<<<NTOK * DIM / 4 / 256, 256, 0, stream>>>(x, xa_ws);
  transpose_cast_kernel<<<dim3(3 * DIM / 32, DIM / 32), dim3(32, 8), 0, stream>>>(Wqkv, wqkvt, DIM, 3 * DIM);
  transpose_cast_kernel<<<dim3(DIM / 32, DIM / 32), dim3(32, 8), 0, stream>>>(Wproj, wprojt, DIM, DIM);
  gemm_kernel<0><<<dim3(3 * DIM / 128, NTOK / 128), 256, 0, stream>>>(xa_ws, wqkvt, nullptr, qkv_ws, nullptr);
  attn_kernel<<<BATCH * HEADS, 256, 0, stream>>>(qkv_ws, static_a, xa_ws);
  gemm_kernel<1><<<dim3(DIM / 128, NTOK / 128), 256, 0, stream>>>(xa_ws, wprojt, bproj, nullptr, out);
}

// Round 2
// 249.826 us; speedup vs baseline: 1.0641x; 1.0641x over previous
//
#include <hip/hip_runtime.h>
#include <stdint.h>

#define DIM 768
#define HEADS 12
#define SEQ 196
#define BATCH 64
#define NTOK (BATCH*SEQ)   // 12544
#define SCALE 0.125f       // 64^-0.5

using short8  = __attribute__((ext_vector_type(8))) short;
using short4v = __attribute__((ext_vector_type(4))) short;
using float4v = __attribute__((ext_vector_type(4))) float;
using ushort4v = __attribute__((ext_vector_type(4))) unsigned short;

static __device__ __forceinline__ unsigned short f2bf(float f) {
  union { float f; unsigned u; } v; v.f = f;
  unsigned u = v.u;
  u += 0x7fffu + ((u >> 16) & 1u);   // RNE
  return (unsigned short)(u >> 16);
}

#if defined(__has_builtin)
#if __has_builtin(__builtin_amdgcn_global_load_lds)
#define HAS_GLL 1
#endif
#endif

// Stage 16B/lane: global (per-lane ptr g) -> LDS (wave-uniform base l, lane*16B apart)
static __device__ __forceinline__ void gll16(const unsigned short* g, unsigned short* l) {
#ifdef HAS_GLL
  __builtin_amdgcn_global_load_lds(
      (const __attribute__((address_space(1))) void*)g,
      (__attribute__((address_space(3))) void*)l, 16, 0, 0);
#else
  const int lane = threadIdx.x & 63;
  *(short8*)(l + lane * 8) = *(const short8*)g;
#endif
}

// ---------------- pre-pass: cast x fp32 -> bf16 ----------------
__global__ __launch_bounds__(256) void cast_x_kernel(const float* __restrict__ in,
                                                     unsigned short* __restrict__ out) {
  int i = blockIdx.x * 256 + threadIdx.x;      // exactly NTOK*DIM/4 threads
  float4 v = ((const float4*)in)[i];
  ushort4v o;
  o.x = f2bf(v.x); o.y = f2bf(v.y); o.z = f2bf(v.z); o.w = f2bf(v.w);
  ((ushort4v*)out)[i] = o;
}

// ---------------- pre-pass: transpose + cast W [R][C] fp32 -> Wt [C][R] bf16 ----------------
__global__ __launch_bounds__(256) void transpose_cast_kernel(const float* __restrict__ in,
                                                             unsigned short* __restrict__ out,
                                                             int R, int C) {
  __shared__ float tile[32][33];
  int c0 = blockIdx.x * 32, r0 = blockIdx.y * 32;
  int tx = threadIdx.x, ty = threadIdx.y;      // (32,8)
  for (int i = 0; i < 32; i += 8)
    tile[ty + i][tx] = in[(size_t)(r0 + ty + i) * C + c0 + tx];
  __syncthreads();
  for (int i = 0; i < 32; i += 8)
    out[(size_t)(c0 + ty + i) * R + r0 + tx] = f2bf(tile[tx][ty + i]);
}

// ---------------- GEMM: C[M][N] = A[M][768] * Bt[N][768]^T, 128x128 tile ----------------
// MODE 0: write bf16 QKV scattered into [3][B][H][S][64]
// MODE 1: write fp32 out[m][n] + bias[n]
template <int MODE>
__global__ __launch_bounds__(256) void gemm_kernel(const unsigned short* __restrict__ A,
                                                   const unsigned short* __restrict__ Bt,
                                                   const float* __restrict__ bias,
                                                   unsigned short* __restrict__ outQKV,
                                                   float* __restrict__ outF) {
  constexpr int K = 768;
  __shared__ __align__(16) unsigned short Als[128 * 32];
  __shared__ __align__(16) unsigned short Bls[128 * 32];
  const int tid = threadIdx.x;
  const int wid = tid >> 6, lane = tid & 63;
  const int s = lane & 15, q = lane >> 4;
  const int wr = wid >> 1, wc = wid & 1;           // 2x2 wave grid, 64x64 per wave
  const int m0 = blockIdx.y * 128;
  const int n0 = blockIdx.x * 128;

  float4v acc[4][4];
  for (int i = 0; i < 4; i++)
    for (int j = 0; j < 4; j++) acc[i][j] = (float4v){0.f, 0.f, 0.f, 0.f};

  const int srow = lane >> 2;           // 0..15
  const int scol = (lane & 3) * 8;      // elements (16B)

  for (int kt = 0; kt < K; kt += 32) {
    const unsigned short* ga = A  + (size_t)(m0 + wid * 32 + srow) * K + kt + scol;
    const unsigned short* gb = Bt + (size_t)(n0 + wid * 32 + srow) * K + kt + scol;
    unsigned short* la = &Als[wid * 32 * 32];
    unsigned short* lb = &Bls[wid * 32 * 32];
    gll16(ga,           la);
    gll16(ga + 16 * K,  la + 16 * 32);
    gll16(gb,           lb);
    gll16(gb + 16 * K,  lb + 16 * 32);
    __syncthreads();   // drains vmcnt -> staged data visible

    short8 af[4], bf[4];
    for (int i = 0; i < 4; i++)
      af[i] = *(const short8*)&Als[(wr * 64 + i * 16 + s) * 32 + q * 8];
    for (int j = 0; j < 4; j++)
      bf[j] = *(const short8*)&Bls[(wc * 64 + j * 16 + s) * 32 + q * 8];
    for (int i = 0; i < 4; i++)
      for (int j = 0; j < 4; j++)
        acc[i][j] = __builtin_amdgcn_mfma_f32_16x16x32_bf16(af[i], bf[j], acc[i][j], 0, 0, 0);
    __syncthreads();   // before next overwrite
  }

  // epilogue: C/D layout col = lane&15, row = q*4 + reg
  for (int i = 0; i < 4; i++) {
    int mbase = m0 + wr * 64 + i * 16 + q * 4;
    for (int j = 0; j < 4; j++) {
      int ng = n0 + wc * 64 + j * 16 + s;
      if (MODE == 0) {
        int t = ng / 768, rem = ng % 768;
        int h = rem >> 6, d = rem & 63;
        for (int r = 0; r < 4; r++) {
          int mg = mbase + r;
          int b = mg / 196, ns = mg - b * 196;
          size_t off = ((size_t)((t * BATCH + b) * HEADS + h) * SEQ + ns) * 64 + d;
          outQKV[off] = f2bf(acc[i][j][r]);
        }
      } else {
        float bv = bias[ng];
        for (int r = 0; r < 4; r++)
          outF[(size_t)(mbase + r) * 768 + ng] = acc[i][j][r] + bv;
      }
    }
  }
}

// ---------------- attention: one block per (b,h), S^T formulation ----------------
// S^T = K_perm . Q^T via mfma (A=K rows permuted, B=Q rows).
// Lane (s,q) holds S^T[m = t*32 + q*8 + h4*4 + i][n = n0+s] for tile tt=2t+h4, reg i.
// After softmax (per-column n: in-register + 2 shuffles), the bf16 values are
// ALREADY in mfma-B-frag layout for O^T = V^T . P^T (k-tile t: k = q*8 + j).
// No LDS round trip for P. Only V^T is staged in LDS.
__global__ __launch_bounds__(256) void attn_kernel(const unsigned short* __restrict__ qkv,
                                                   const float* __restrict__ static_a,
                                                   unsigned short* __restrict__ outA) {
  constexpr int WV = 228;   // stride: 114 dwords == 18 mod 32 -> b64 frag reads conflict-free
  __shared__ __align__(16) unsigned short Vt[64 * WV];   // V^T [d][m], m zero-padded to 224
  const int tid = threadIdx.x, wid = tid >> 6, lane = tid & 63;
  const int s = lane & 15, q = lane >> 4;
  const int bh = blockIdx.x;
  const int b = bh / 12, h = bh % 12;
  const size_t slab = (size_t)SEQ * 64;
  const unsigned short* Qb = qkv + (size_t)(0 * BATCH * HEADS + bh) * slab;
  const unsigned short* Kb = qkv + (size_t)(1 * BATCH * HEADS + bh) * slab;
  const unsigned short* Vb = qkv + (size_t)(2 * BATCH * HEADS + bh) * slab;

  // stage V^T: thread covers m = mb*64 + (tid&63), d = d0..d0+15
  {
    const int ms = tid & 63;
    const int d0 = (tid >> 6) * 16;
    for (int mb = 0; mb < 4; ++mb) {
      int m = mb * 64 + ms;
      if (m < 224) {
        if (m < 196) {
          short8 v0 = *(const short8*)&Vb[(size_t)m * 64 + d0];
          short8 v1 = *(const short8*)&Vb[(size_t)m * 64 + d0 + 8];
          for (int j = 0; j < 8; j++) Vt[(d0 + j) * WV + m] = (unsigned short)v0[j];
          for (int j = 0; j < 8; j++) Vt[(d0 + 8 + j) * WV + m] = (unsigned short)v1[j];
        } else {
          for (int j = 0; j < 16; j++) Vt[(d0 + j) * WV + m] = 0;
        }
      }
    }
  }
  __syncthreads();

  const int pmbase = (s >> 2) * 8 + (s & 3);   // permuted K-row base for A-frag row s

  for (int qt = wid; qt < 13; qt += 4) {
    const int n0 = qt * 16;
    const int nq = n0 + s;
    const int nql = nq > 195 ? 195 : nq;
    short8 qf0 = *(const short8*)&Qb[(size_t)nql * 64 + q * 8];
    short8 qf1 = *(const short8*)&Qb[(size_t)nql * 64 + 32 + q * 8];

    // S^T tiles: tt = 0..12 (tt = 2t + h4; tile (t=6,h4=1) is entirely m>=196 -> skipped)
    float4v sacc[14];
    for (int tt = 0; tt < 13; tt++) {
      int t = tt >> 1, h4 = tt & 1;
      int m = t * 32 + h4 * 4 + pmbase;
      if (m > 195) m = 195;                       // garbage rows, masked later
      short8 kf0 = *(const short8*)&Kb[(size_t)m * 64 + q * 8];
      short8 kf1 = *(const short8*)&Kb[(size_t)m * 64 + 32 + q * 8];
      float4v z = (float4v){0.f, 0.f, 0.f, 0.f};
      z = __builtin_amdgcn_mfma_f32_16x16x32_bf16(kf0, qf0, z, 0, 0, 0);
      z = __builtin_amdgcn_mfma_f32_16x16x32_bf16(kf1, qf1, z, 0, 0, 0);
      sacc[tt] = z;
    }
    sacc[13] = (float4v){0.f, 0.f, 0.f, 0.f};

    // column softmax: lane owns column n. Valid m: tt<12 all; tt==12 only q==0.
    float mx = -3.0e38f;
    for (int tt = 0; tt < 12; tt++)
      for (int i = 0; i < 4; i++) mx = fmaxf(mx, sacc[tt][i]);
    if (q == 0)
      for (int i = 0; i < 4; i++) mx = fmaxf(mx, sacc[12][i]);
    mx = fmaxf(mx, __shfl_xor(mx, 16));
    mx = fmaxf(mx, __shfl_xor(mx, 32));
    const float CE = SCALE * 1.44269504f;
    float sm = 0.f;
    for (int tt = 0; tt < 12; tt++)
      for (int i = 0; i < 4; i++) {
        float e = __builtin_amdgcn_exp2f((sacc[tt][i] - mx) * CE);
        sacc[tt][i] = e; sm += e;
      }
    if (q == 0) {
      for (int i = 0; i < 4; i++) {
        float e = __builtin_amdgcn_exp2f((sacc[12][i] - mx) * CE);
        sacc[12][i] = e; sm += e;
      }
    } else {
      sacc[12] = (float4v){0.f, 0.f, 0.f, 0.f};
    }
    sm += __shfl_xor(sm, 16);
    sm += __shfl_xor(sm, 32);
    const float inv = 1.0f / sm;

    // P^T fragments: pfrag[t][j] = P^T[m = t*32 + q*8 + j][n], j = h4*4 + i
    const float* sa = static_a + ((size_t)h * SEQ + nql) * SEQ;
    short8 pfrag[7];
    for (int t = 0; t < 7; t++) {
      short8 pf;
      for (int h4 = 0; h4 < 2; h4++) {
        int tt = 2 * t + h4;
        bool valid = (tt < 12) || (tt == 12 && q == 0);
        float4v a4 = (float4v){0.f, 0.f, 0.f, 0.f};
        if (valid) a4 = *(const float4v*)(sa + t * 32 + q * 8 + h4 * 4);
        int src = valid ? tt : 13;
        for (int i = 0; i < 4; i++) {
          float pv = valid ? (sacc[src][i] * inv + a4[i]) : 0.f;
          pf[h4 * 4 + i] = (short)f2bf(pv);
        }
      }
      pfrag[t] = pf;
    }

    // O^T = V^T . P^T : A-frag = V^T rows (from LDS, two b64 reads), B-frag = pfrag
    for (int dt = 0; dt < 4; dt++) {
      float4v o = (float4v){0.f, 0.f, 0.f, 0.f};
      for (int t = 0; t < 7; t++) {
        const unsigned short* vp = &Vt[(dt * 16 + s) * WV + t * 32 + q * 8];
        short4v v0 = *(const short4v*)vp;
        short4v v1 = *(const short4v*)(vp + 4);
        short8 vf;
        vf[0] = v0[0]; vf[1] = v0[1]; vf[2] = v0[2]; vf[3] = v0[3];
        vf[4] = v1[0]; vf[5] = v1[1]; vf[6] = v1[2]; vf[7] = v1[3];
        o = __builtin_amdgcn_mfma_f32_16x16x32_bf16(vf, pfrag[t], o, 0, 0, 0);
      }
      // lane holds O^T[d = dt*16 + q*4 + r][n = nq]
      if (nq < 196) {
        ushort4v ov;
        ov.x = f2bf(o[0]); ov.y = f2bf(o[1]); ov.z = f2bf(o[2]); ov.w = f2bf(o[3]);
        *(ushort4v*)&outA[((size_t)b * SEQ + nq) * DIM + h * 64 + dt * 16 + q * 4] = ov;
      }
    }
  }
}

extern "C" void kernel_launch(void* const* d_in, const int* in_sizes, int n_in,
                              void* d_out, int out_size, void* d_ws, size_t ws_size,
                              hipStream_t stream) {
  const float* x        = (const float*)d_in[0];
  const float* Wqkv     = (const float*)d_in[1];
  const float* static_a = (const float*)d_in[2];
  const float* Wproj    = (const float*)d_in[3];
  const float* bproj    = (const float*)d_in[4];
  float* out = (float*)d_out;

  unsigned char* ws = (unsigned char*)d_ws;
  size_t off = 0;
  unsigned short* qkv_ws = (unsigned short*)(ws + off); off += (size_t)3 * NTOK * DIM * 2; // 57.8 MB
  unsigned short* xa_ws  = (unsigned short*)(ws + off); off += (size_t)NTOK * DIM * 2;     // x_bf16, reused as attn-out
  unsigned short* wqkvt  = (unsigned short*)(ws + off); off += (size_t)3 * DIM * DIM * 2;  // W_qkv^T bf16
  unsigned short* wprojt = (unsigned short*)(ws + off); off += (size_t)DIM * DIM * 2;      // W_proj^T bf16

  cast_x_kernel<<<NTOK * DIM / 4 / 256, 256, 0, stream>>>(x, xa_ws);
  transpose_cast_kernel<<<dim3(3 * DIM / 32, DIM / 32), dim3(32, 8), 0, stream>>>(Wqkv, wqkvt, DIM, 3 * DIM);
  transpose_cast_kernel<<<dim3(DIM / 32, DIM / 32), dim3(32, 8), 0, stream>>>(Wproj, wprojt, DIM, DIM);
  gemm_kernel<0><<<dim3(3 * DIM / 128, NTOK / 128), 256, 0, stream>>>(xa_ws, wqkvt, nullptr, qkv_ws, nullptr);
  attn_kernel<<<BATCH * HEADS, 256, 0, stream>>>(qkv_ws, static_a, xa_ws);
  gemm_kernel<1><<<dim3(DIM / 128, NTOK / 128), 256, 0, stream>>>(xa_ws, wprojt, bproj, nullptr, out);
}

// Round 3
// 248.958 us; speedup vs baseline: 1.0678x; 1.0035x over previous
//
#include <hip/hip_runtime.h>
#include <stdint.h>

#define DIM 768
#define HEADS 12
#define SEQ 196
#define BATCH 64
#define NTOK (BATCH*SEQ)   // 12544
#define QKVLD (3*DIM)      // 2304, row stride of qkv workspace
#define SCALE 0.125f       // 64^-0.5

using short8  = __attribute__((ext_vector_type(8))) short;
using short4v = __attribute__((ext_vector_type(4))) short;
using float4v = __attribute__((ext_vector_type(4))) float;
using ushort4v = __attribute__((ext_vector_type(4))) unsigned short;

static __device__ __forceinline__ unsigned short f2bf(float f) {
  union { float f; unsigned u; } v; v.f = f;
  unsigned u = v.u;
  u += 0x7fffu + ((u >> 16) & 1u);   // RNE
  return (unsigned short)(u >> 16);
}

#if defined(__has_builtin)
#if __has_builtin(__builtin_amdgcn_global_load_lds)
#define HAS_GLL 1
#endif
#endif

// Stage 16B/lane: global (per-lane ptr g) -> LDS (wave-uniform base l, lane*16B apart)
static __device__ __forceinline__ void gll16(const unsigned short* g, unsigned short* l) {
#ifdef HAS_GLL
  __builtin_amdgcn_global_load_lds(
      (const __attribute__((address_space(1))) void*)g,
      (__attribute__((address_space(3))) void*)l, 16, 0, 0);
#else
  const int lane = threadIdx.x & 63;
  *(short8*)(l + lane * 8) = *(const short8*)g;
#endif
}

// ---------------- pre-pass: cast x fp32 -> bf16 ----------------
__global__ __launch_bounds__(256) void cast_x_kernel(const float* __restrict__ in,
                                                     unsigned short* __restrict__ out) {
  int i = blockIdx.x * 256 + threadIdx.x;      // exactly NTOK*DIM/4 threads
  float4 v = ((const float4*)in)[i];
  ushort4v o;
  o.x = f2bf(v.x); o.y = f2bf(v.y); o.z = f2bf(v.z); o.w = f2bf(v.w);
  ((ushort4v*)out)[i] = o;
}

// ---------------- pre-pass: transpose + cast W [R][C] fp32 -> Wt [C][R] bf16 ----------------
__global__ __launch_bounds__(256) void transpose_cast_kernel(const float* __restrict__ in,
                                                             unsigned short* __restrict__ out,
                                                             int R, int C) {
  __shared__ float tile[32][33];
  int c0 = blockIdx.x * 32, r0 = blockIdx.y * 32;
  int tx = threadIdx.x, ty = threadIdx.y;      // (32,8)
  for (int i = 0; i < 32; i += 8)
    tile[ty + i][tx] = in[(size_t)(r0 + ty + i) * C + c0 + tx];
  __syncthreads();
  for (int i = 0; i < 32; i += 8)
    out[(size_t)(c0 + ty + i) * R + r0 + tx] = f2bf(tile[tx][ty + i]);
}

// ---------------- GEMM: C[M][N] = A[M][768] * Bt[N][768]^T, 128x128 tile ----------------
// MODE 0: C^T-register formulation, bf16 out row-major [M][2304] (packed 8B stores)
// MODE 1: fp32 out[m][768] + bias[n]
template <int MODE>
__global__ __launch_bounds__(256) void gemm_kernel(const unsigned short* __restrict__ A,
                                                   const unsigned short* __restrict__ Bt,
                                                   const float* __restrict__ bias,
                                                   unsigned short* __restrict__ outB,
                                                   float* __restrict__ outF) {
  constexpr int K = 768;
  __shared__ __align__(16) unsigned short Als[128 * 32];
  __shared__ __align__(16) unsigned short Bls[128 * 32];
  const int tid = threadIdx.x;
  const int wid = tid >> 6, lane = tid & 63;
  const int s = lane & 15, q = lane >> 4;
  const int wr = wid >> 1, wc = wid & 1;           // 2x2 wave grid, 64x64 per wave

  // XCD-aware swizzle: HW round-robins linear block id over 8 XCDs; remap so each
  // XCD gets a CONTIGUOUS id range -> B-panel (3.5MB) stays L2-resident per XCD.
  const int nbx = gridDim.x;
  const int nb = gridDim.x * gridDim.y;
  int id = blockIdx.y * nbx + blockIdx.x;
  {
    int x = id & 7, lid = id >> 3;
    int per = nb >> 3, big = nb & 7;
    id = (x < big) ? x * (per + 1) + lid
                   : big * (per + 1) + (x - big) * per + lid;
  }
  const int m0 = (id / nbx) * 128;
  const int n0 = (id % nbx) * 128;

  float4v acc[4][4];
  for (int i = 0; i < 4; i++)
    for (int j = 0; j < 4; j++) acc[i][j] = (float4v){0.f, 0.f, 0.f, 0.f};

  const int srow = lane >> 2;           // 0..15
  const int scol = (lane & 3) * 8;      // elements (16B)

  const unsigned short* ga = A  + (size_t)(m0 + wid * 32 + srow) * K + scol;
  const unsigned short* gb = Bt + (size_t)(n0 + wid * 32 + srow) * K + scol;
  unsigned short* la = &Als[wid * 32 * 32];
  unsigned short* lb = &Bls[wid * 32 * 32];

  for (int kt = 0; kt < K; kt += 32) {
    gll16(ga,           la);
    gll16(ga + 16 * K,  la + 16 * 32);
    gll16(gb,           lb);
    gll16(gb + 16 * K,  lb + 16 * 32);
    ga += 32; gb += 32;
    __syncthreads();   // drains vmcnt -> staged data visible

    short8 af[4], bf[4];
    for (int i = 0; i < 4; i++)
      af[i] = *(const short8*)&Als[(wr * 64 + i * 16 + s) * 32 + q * 8];
    for (int j = 0; j < 4; j++)
      bf[j] = *(const short8*)&Bls[(wc * 64 + j * 16 + s) * 32 + q * 8];
    for (int i = 0; i < 4; i++)
      for (int j = 0; j < 4; j++) {
        if (MODE == 0)   // C^T: lane (s,q) gets C[m=i*16+s][n=j*16+q*4+r]
          acc[i][j] = __builtin_amdgcn_mfma_f32_16x16x32_bf16(bf[j], af[i], acc[i][j], 0, 0, 0);
        else             // C:   lane (s,q) gets C[m=i*16+q*4+r][n=j*16+s]
          acc[i][j] = __builtin_amdgcn_mfma_f32_16x16x32_bf16(af[i], bf[j], acc[i][j], 0, 0, 0);
      }
    __syncthreads();   // before next overwrite
  }

  if (MODE == 0) {
    // row-major bf16 [M][2304]; per (i,j) one packed ushort4 (8B) store
    for (int i = 0; i < 4; i++) {
      size_t mrow = (size_t)(m0 + wr * 64 + i * 16 + s) * QKVLD;
      for (int j = 0; j < 4; j++) {
        int n = n0 + wc * 64 + j * 16 + q * 4;
        ushort4v ov;
        ov.x = f2bf(acc[i][j][0]); ov.y = f2bf(acc[i][j][1]);
        ov.z = f2bf(acc[i][j][2]); ov.w = f2bf(acc[i][j][3]);
        *(ushort4v*)&outB[mrow + n] = ov;
      }
    }
  } else {
    for (int i = 0; i < 4; i++) {
      int mbase = m0 + wr * 64 + i * 16 + q * 4;
      for (int j = 0; j < 4; j++) {
        int ng = n0 + wc * 64 + j * 16 + s;
        float bv = bias[ng];
        for (int r = 0; r < 4; r++)
          outF[(size_t)(mbase + r) * 768 + ng] = acc[i][j][r] + bv;
      }
    }
  }
}

// ---------------- attention: one block per (b,h), S^T formulation ----------------
// qkv workspace is [NTOK][2304] row-major: token row b*196+n, cols h*64+d (Q),
// 768+h*64+d (K), 1536+h*64+d (V). All fragment reads stay 16B-contiguous.
__global__ __launch_bounds__(256) void attn_kernel(const unsigned short* __restrict__ qkv,
                                                   const float* __restrict__ static_a,
                                                   unsigned short* __restrict__ outA) {
  constexpr int WV = 228;   // stride: 114 dwords == 18 mod 32 -> b64 frag reads conflict-free
  __shared__ __align__(16) unsigned short Vt[64 * WV];   // V^T [d][m], m zero-padded to 224
  const int tid = threadIdx.x, wid = tid >> 6, lane = tid & 63;
  const int s = lane & 15, q = lane >> 4;
  const int bh = blockIdx.x;
  const int b = bh / 12, h = bh % 12;
  const unsigned short* Qb = qkv + (size_t)b * SEQ * QKVLD + h * 64;
  const unsigned short* Kb = Qb + 768;
  const unsigned short* Vb = Qb + 1536;

  // stage V^T: thread covers m = mb*64 + (tid&63), d = d0..d0+15
  {
    const int ms = tid & 63;
    const int d0 = (tid >> 6) * 16;
    for (int mb = 0; mb < 4; ++mb) {
      int m = mb * 64 + ms;
      if (m < 224) {
        if (m < 196) {
          short8 v0 = *(const short8*)&Vb[(size_t)m * QKVLD + d0];
          short8 v1 = *(const short8*)&Vb[(size_t)m * QKVLD + d0 + 8];
          for (int j = 0; j < 8; j++) Vt[(d0 + j) * WV + m] = (unsigned short)v0[j];
          for (int j = 0; j < 8; j++) Vt[(d0 + 8 + j) * WV + m] = (unsigned short)v1[j];
        } else {
          for (int j = 0; j < 16; j++) Vt[(d0 + j) * WV + m] = 0;
        }
      }
    }
  }
  __syncthreads();

  const int pmbase = (s >> 2) * 8 + (s & 3);   // permuted K-row base for A-frag row s

  for (int qt = wid; qt < 13; qt += 4) {
    const int n0 = qt * 16;
    const int nq = n0 + s;
    const int nql = nq > 195 ? 195 : nq;
    short8 qf0 = *(const short8*)&Qb[(size_t)nql * QKVLD + q * 8];
    short8 qf1 = *(const short8*)&Qb[(size_t)nql * QKVLD + 32 + q * 8];

    // S^T tiles: tt = 0..12 (tt = 2t + h4; tile (t=6,h4=1) is entirely m>=196 -> skipped)
    float4v sacc[14];
    for (int tt = 0; tt < 13; tt++) {
      int t = tt >> 1, h4 = tt & 1;
      int m = t * 32 + h4 * 4 + pmbase;
      if (m > 195) m = 195;                       // garbage rows, masked later
      short8 kf0 = *(const short8*)&Kb[(size_t)m * QKVLD + q * 8];
      short8 kf1 = *(const short8*)&Kb[(size_t)m * QKVLD + 32 + q * 8];
      float4v z = (float4v){0.f, 0.f, 0.f, 0.f};
      z = __builtin_amdgcn_mfma_f32_16x16x32_bf16(kf0, qf0, z, 0, 0, 0);
      z = __builtin_amdgcn_mfma_f32_16x16x32_bf16(kf1, qf1, z, 0, 0, 0);
      sacc[tt] = z;
    }
    sacc[13] = (float4v){0.f, 0.f, 0.f, 0.f};

    // column softmax: lane owns column n. Valid m: tt<12 all; tt==12 only q==0.
    float mx = -3.0e38f;
    for (int tt = 0; tt < 12; tt++)
      for (int i = 0; i < 4; i++) mx = fmaxf(mx, sacc[tt][i]);
    if (q == 0)
      for (int i = 0; i < 4; i++) mx = fmaxf(mx, sacc[12][i]);
    mx = fmaxf(mx, __shfl_xor(mx, 16));
    mx = fmaxf(mx, __shfl_xor(mx, 32));
    const float CE = SCALE * 1.44269504f;
    float sm = 0.f;
    for (int tt = 0; tt < 12; tt++)
      for (int i = 0; i < 4; i++) {
        float e = __builtin_amdgcn_exp2f((sacc[tt][i] - mx) * CE);
        sacc[tt][i] = e; sm += e;
      }
    if (q == 0) {
      for (int i = 0; i < 4; i++) {
        float e = __builtin_amdgcn_exp2f((sacc[12][i] - mx) * CE);
        sacc[12][i] = e; sm += e;
      }
    } else {
      sacc[12] = (float4v){0.f, 0.f, 0.f, 0.f};
    }
    sm += __shfl_xor(sm, 16);
    sm += __shfl_xor(sm, 32);
    const float inv = 1.0f / sm;

    // P^T fragments: pfrag[t][j] = P^T[m = t*32 + q*8 + j][n], j = h4*4 + i
    const float* sa = static_a + ((size_t)h * SEQ + nql) * SEQ;
    short8 pfrag[7];
    for (int t = 0; t < 7; t++) {
      short8 pf;
      for (int h4 = 0; h4 < 2; h4++) {
        int tt = 2 * t + h4;
        bool valid = (tt < 12) || (tt == 12 && q == 0);
        float4v a4 = (float4v){0.f, 0.f, 0.f, 0.f};
        if (valid) a4 = *(const float4v*)(sa + t * 32 + q * 8 + h4 * 4);
        int src = valid ? tt : 13;
        for (int i = 0; i < 4; i++) {
          float pv = valid ? (sacc[src][i] * inv + a4[i]) : 0.f;
          pf[h4 * 4 + i] = (short)f2bf(pv);
        }
      }
      pfrag[t] = pf;
    }

    // O^T = V^T . P^T : A-frag = V^T rows (from LDS, two b64 reads), B-frag = pfrag
    for (int dt = 0; dt < 4; dt++) {
      float4v o = (float4v){0.f, 0.f, 0.f, 0.f};
      for (int t = 0; t < 7; t++) {
        const unsigned short* vp = &Vt[(dt * 16 + s) * WV + t * 32 + q * 8];
        short4v v0 = *(const short4v*)vp;
        short4v v1 = *(const short4v*)(vp + 4);
        short8 vf;
        vf[0] = v0[0]; vf[1] = v0[1]; vf[2] = v0[2]; vf[3] = v0[3];
        vf[4] = v1[0]; vf[5] = v1[1]; vf[6] = v1[2]; vf[7] = v1[3];
        o = __builtin_amdgcn_mfma_f32_16x16x32_bf16(vf, pfrag[t], o, 0, 0, 0);
      }
      // lane holds O^T[d = dt*16 + q*4 + r][n = nq]
      if (nq < 196) {
        ushort4v ov;
        ov.x = f2bf(o[0]); ov.y = f2bf(o[1]); ov.z = f2bf(o[2]); ov.w = f2bf(o[3]);
        *(ushort4v*)&outA[((size_t)b * SEQ + nq) * DIM + h * 64 + dt * 16 + q * 4] = ov;
      }
    }
  }
}

extern "C" void kernel_launch(void* const* d_in, const int* in_sizes, int n_in,
                              void* d_out, int out_size, void* d_ws, size_t ws_size,
                              hipStream_t stream) {
  const float* x        = (const float*)d_in[0];
  const float* Wqkv     = (const float*)d_in[1];
  const float* static_a = (const float*)d_in[2];
  const float* Wproj    = (const float*)d_in[3];
  const float* bproj    = (const float*)d_in[4];
  float* out = (float*)d_out;

  unsigned char* ws = (unsigned char*)d_ws;
  size_t off = 0;
  unsigned short* qkv_ws = (unsigned short*)(ws + off); off += (size_t)NTOK * QKVLD * 2;   // 57.8 MB
  unsigned short* xa_ws  = (unsigned short*)(ws + off); off += (size_t)NTOK * DIM * 2;     // x_bf16, reused as attn-out
  unsigned short* wqkvt  = (unsigned short*)(ws + off); off += (size_t)3 * DIM * DIM * 2;  // W_qkv^T bf16
  unsigned short* wprojt = (unsigned short*)(ws + off); off += (size_t)DIM * DIM * 2;      // W_proj^T bf16

  cast_x_kernel<<<NTOK * DIM / 4 / 256, 256, 0, stream>>>(x, xa_ws);
  transpose_cast_kernel<<<dim3(3 * DIM / 32, DIM / 32), dim3(32, 8), 0, stream>>>(Wqkv, wqkvt, DIM, 3 * DIM);
  transpose_cast_kernel<<<dim3(DIM / 32, DIM / 32), dim3(32, 8), 0, stream>>>(Wproj, wprojt, DIM, DIM);
  gemm_kernel<0><<<dim3(3 * DIM / 128, NTOK / 128), 256, 0, stream>>>(xa_ws, wqkvt, nullptr, qkv_ws, nullptr);
  attn_kernel<<<BATCH * HEADS, 256, 0, stream>>>(qkv_ws, static_a, xa_ws);
  gemm_kernel<1><<<dim3(DIM / 128, NTOK / 128), 256, 0, stream>>>(xa_ws, wprojt, bproj, nullptr, out);
}